// Round 1
// baseline (412.542 us; speedup 1.0000x reference)
//
#include <hip/hip_runtime.h>
#include <cstdint>

// NeuralRadiance: hash-grid embedding gather + MLP 19->64->64->3 + sigmoid.
// Round 1: correct fp32 baseline. One thread per point; weights fetched via
// wave-uniform addresses -> scalar loads (s_load_dwordx4) from constant cache,
// keeping the VALU pipe free for the 5504 FMAs/point. Layer 3 fused into
// layer 2 epilogue so h2[64] never exists; register peak ~100 VGPRs.

__global__ __launch_bounds__(256) void nrad_fp32_kernel(
    const float* __restrict__ pos, const float* __restrict__ nrm,
    const float* __restrict__ emb,
    const float* __restrict__ W1, const float* __restrict__ b1,
    const float* __restrict__ W2, const float* __restrict__ b2,
    const float* __restrict__ W3, const float* __restrict__ b3,
    float* __restrict__ out, int n)
{
    int i = blockIdx.x * blockDim.x + threadIdx.x;
    if (i >= n) return;

    // ---- hash index (matches torch/.astype(int32) trunc-toward-zero, int32 wrap)
    float p0 = pos[3*i+0], p1 = pos[3*i+1], p2 = pos[3*i+2];
    int s0 = (int)(p0 * 8.0f);
    int s1 = (int)(p1 * 8.0f);
    int s2 = (int)(p2 * 8.0f);
    uint32_t h = ((uint32_t)s0 * 73856093u) ^
                 ((uint32_t)s1 * 19349663u) ^
                 ((uint32_t)s2 * 83492791u);
    uint32_t idx = h & 32767u;

    // ---- gather 16-float embedding row (64B aligned) + normal
    const float4* e4 = (const float4*)(emb + (size_t)idx * 16);
    float4 f0 = e4[0], f1 = e4[1], f2 = e4[2], f3 = e4[3];

    float x[19];
    x[0]=f0.x;  x[1]=f0.y;  x[2]=f0.z;  x[3]=f0.w;
    x[4]=f1.x;  x[5]=f1.y;  x[6]=f1.z;  x[7]=f1.w;
    x[8]=f2.x;  x[9]=f2.y;  x[10]=f2.z; x[11]=f2.w;
    x[12]=f3.x; x[13]=f3.y; x[14]=f3.z; x[15]=f3.w;
    x[16]=nrm[3*i+0]; x[17]=nrm[3*i+1]; x[18]=nrm[3*i+2];

    // ---- layer 1: 19 -> 64, relu. Fully unrolled so h1v[] has only
    // compile-time indices (stays in VGPRs). Weight slice W1[k*64+j4*4 .. +3]
    // is wave-uniform & 16B-aligned -> s_load_dwordx4.
    float h1v[64];
    #pragma unroll
    for (int j4 = 0; j4 < 16; ++j4) {
        const float4 bb = *(const float4*)(b1 + j4*4);
        float a0 = bb.x, a1 = bb.y, a2 = bb.z, a3 = bb.w;
        #pragma unroll
        for (int k = 0; k < 19; ++k) {
            const float4 w = *(const float4*)(W1 + k*64 + j4*4);
            float xv = x[k];
            a0 += xv * w.x; a1 += xv * w.y; a2 += xv * w.z; a3 += xv * w.w;
        }
        h1v[j4*4+0] = fmaxf(a0, 0.0f);
        h1v[j4*4+1] = fmaxf(a1, 0.0f);
        h1v[j4*4+2] = fmaxf(a2, 0.0f);
        h1v[j4*4+3] = fmaxf(a3, 0.0f);
    }

    // ---- layer 2 (64->64, relu) with layer 3 (64->3) fused into epilogue.
    // Outer loop NOT unrolled (code size); inner k fully unrolled so h1v[k]
    // reads are compile-time indexed.
    float o0 = b3[0], o1 = b3[1], o2 = b3[2];
    for (int j4 = 0; j4 < 16; ++j4) {
        const float4 bb = *(const float4*)(b2 + j4*4);
        float a0 = bb.x, a1 = bb.y, a2 = bb.z, a3 = bb.w;
        #pragma unroll
        for (int k = 0; k < 64; ++k) {
            const float4 w = *(const float4*)(W2 + k*64 + j4*4);
            float hv = h1v[k];
            a0 += hv * w.x; a1 += hv * w.y; a2 += hv * w.z; a3 += hv * w.w;
        }
        a0 = fmaxf(a0, 0.0f); a1 = fmaxf(a1, 0.0f);
        a2 = fmaxf(a2, 0.0f); a3 = fmaxf(a3, 0.0f);
        int j = j4 * 4;
        o0 += a0 * W3[(j+0)*3+0]; o1 += a0 * W3[(j+0)*3+1]; o2 += a0 * W3[(j+0)*3+2];
        o0 += a1 * W3[(j+1)*3+0]; o1 += a1 * W3[(j+1)*3+1]; o2 += a1 * W3[(j+1)*3+2];
        o0 += a2 * W3[(j+2)*3+0]; o1 += a2 * W3[(j+2)*3+1]; o2 += a2 * W3[(j+2)*3+2];
        o0 += a3 * W3[(j+3)*3+0]; o1 += a3 * W3[(j+3)*3+1]; o2 += a3 * W3[(j+3)*3+2];
    }

    // ---- sigmoid + store
    out[3*i+0] = 1.0f / (1.0f + __expf(-o0));
    out[3*i+1] = 1.0f / (1.0f + __expf(-o1));
    out[3*i+2] = 1.0f / (1.0f + __expf(-o2));
}

extern "C" void kernel_launch(void* const* d_in, const int* in_sizes, int n_in,
                              void* d_out, int out_size, void* d_ws, size_t ws_size,
                              hipStream_t stream) {
    const float* pos = (const float*)d_in[0];
    const float* nrm = (const float*)d_in[1];
    const float* emb = (const float*)d_in[2];
    const float* W1  = (const float*)d_in[3];
    const float* b1  = (const float*)d_in[4];
    const float* W2  = (const float*)d_in[5];
    const float* b2  = (const float*)d_in[6];
    const float* W3  = (const float*)d_in[7];
    const float* b3  = (const float*)d_in[8];
    float* out = (float*)d_out;

    int n = in_sizes[0] / 3;  // N = 2,097,152
    int block = 256;
    int grid = (n + block - 1) / block;
    nrad_fp32_kernel<<<grid, block, 0, stream>>>(pos, nrm, emb, W1, b1, W2, b2,
                                                 W3, b3, out, n);
}

// Round 2
// 178.618 us; speedup vs baseline: 2.3096x; 2.3096x over previous
//
#include <hip/hip_runtime.h>
#include <cstdint>

// NeuralRadiance via bf16 MFMA (16x16x32). Layers:
//   L1 (transposed): h1^T = W1^T @ x^T   -- bias b1 folded as x[k=19]=1.0
//   L2 (transposed): h2^T = W2^T @ h1^T  -- bias b2 via acc init
//   L3 (normal)    : h3   = h2  @ W3     -- bias b3 via acc init
// Fragment facts used (HW-verified per guide):
//   A-frag: lane holds A[m=lane&15][k=quad*8+j], 8 bf16
//   B-frag: lane holds B[k=quad*8+j][n=lane&15], 8 bf16
//   C/D   : lane reg r holds D[m=quad*4+r][n=lane&15], 4 f32
// Transposed orientation keeps pt in lane&15 for BOTH the B-frag read and the
// C write, so every LDS access is contiguous (b128 read / b64 write).

typedef short  bf16x8 __attribute__((ext_vector_type(8)));
typedef float  f32x4  __attribute__((ext_vector_type(4)));

#define MFMA16(A, B, C) __builtin_amdgcn_mfma_f32_16x16x32_bf16((A), (B), (C), 0, 0, 0)

// RNE float->bf16
__device__ inline uint32_t f2b_u(float f) {
    union { float f; uint32_t u; } x; x.f = f;
    return (x.u + 0x7FFFu + ((x.u >> 16) & 1u)) >> 16;
}
__device__ inline short f2b(float f) { return (short)f2b_u(f); }
// pack two f32 -> dword of 2 bf16 (lo = a, hi = b)
__device__ inline int pk(float a, float b) { return (int)(f2b_u(a) | (f2b_u(b) << 16)); }

__device__ inline void lds_fence() {
    __asm__ volatile("s_waitcnt lgkmcnt(0)" ::: "memory");
}

// LDS strides (in shorts). All chosen: multiple of 8 (16B-aligned b128) and
// not 0 mod 64 (dword-bank shift per row -> <=2-way conflicts).
#define XS   40   // x rows: 32 used (19 feat + 1.0 + zero pad)
#define WS   72   // W2T / W3T / h rows: 64 used
#define W1S  40   // W1T rows: 32 used (19 + b1 at k=19 + zeros)

__global__ __launch_bounds__(256) void nrad_mfma_kernel(
    const float* __restrict__ pos, const float* __restrict__ nrm,
    const float* __restrict__ emb,
    const float* __restrict__ W1, const float* __restrict__ b1,
    const float* __restrict__ W2, const float* __restrict__ b2,
    const float* __restrict__ W3, const float* __restrict__ b3,
    float* __restrict__ out, int ntiles)
{
    __shared__ alignas(16) short w1t[64 * W1S];   // [n][k] = W1[k][n]; k==19 -> b1[n]
    __shared__ alignas(16) short w2t[64 * WS];    // [n][k] = W2[k][n]
    __shared__ alignas(16) short w3t[3 * WS];     // [c][k] = W3[k][c]
    __shared__ float b2s[64];
    __shared__ float b3s[4];
    __shared__ alignas(16) short xbuf[4][64 * XS];  // per-wave [pt][k] bf16
    __shared__ alignas(16) short hbuf[4][16 * WS];  // per-wave [pt][feat], h1 then h2

    const int tid  = threadIdx.x;
    const int wave = tid >> 6;
    const int lane = tid & 63;
    const int q    = lane >> 4;   // quad
    const int nn   = lane & 15;

    // ---- one-time: stage transposed bf16 weights into LDS (cooperative)
    for (int e = tid; e < 64 * W1S; e += 256) {
        int n = e / W1S, k = e - n * W1S;
        float v = (k < 19) ? W1[k * 64 + n] : (k == 19 ? b1[n] : 0.0f);
        w1t[n * W1S + k] = f2b(v);
    }
    for (int e = tid; e < 4096; e += 256) {
        int k = e >> 6, n = e & 63;           // read W2 coalesced
        w2t[n * WS + k] = f2b(W2[e]);
    }
    for (int e = tid; e < 192; e += 256) {
        int k = e / 3, c = e - k * 3;
        w3t[c * WS + k] = f2b(W3[e]);
    }
    for (int e = tid; e < 64; e += 256) b2s[e] = b2[e];
    if (tid < 4) b3s[tid] = (tid < 3) ? b3[tid] : 0.0f;
    __syncthreads();

    // ---- per-lane register fragments (persistent across tiles)
    bf16x8 w1f[4], w2f[4][2], w3f[2];
    #pragma unroll
    for (int t = 0; t < 4; ++t)
        w1f[t] = *(const bf16x8*)(w1t + (t * 16 + nn) * W1S + q * 8);
    #pragma unroll
    for (int t = 0; t < 4; ++t)
        #pragma unroll
        for (int ks = 0; ks < 2; ++ks)
            w2f[t][ks] = *(const bf16x8*)(w2t + (t * 16 + nn) * WS + ks * 32 + q * 8);
    {
        int c3 = (nn < 3) ? nn : 0;  // clamped (values unused for nn>=3)
        w3f[0] = *(const bf16x8*)(w3t + c3 * WS + q * 8);
        w3f[1] = *(const bf16x8*)(w3t + c3 * WS + 32 + q * 8);
    }
    float b2r[16];
    #pragma unroll
    for (int t = 0; t < 4; ++t)
        #pragma unroll
        for (int r = 0; r < 4; ++r)
            b2r[t * 4 + r] = b2s[t * 16 + q * 4 + r];
    const float b3r = (nn < 3) ? b3s[nn] : 0.0f;

    short* xw = &xbuf[wave][0];
    short* hw = &hbuf[wave][0];

    const int wave_gid = blockIdx.x * 4 + wave;
    const int nwaves   = gridDim.x * 4;

    for (int tile = wave_gid; tile < ntiles; tile += nwaves) {
        const int base = tile * 64;
        const int i    = base + lane;

        // ---- stage this lane's point into xbuf[pt=lane][k] (bf16)
        const float* pp = pos + 3 * i;
        const float* np = nrm + 3 * i;
        float p0 = pp[0], p1 = pp[1], p2 = pp[2];
        int s0 = (int)(p0 * 8.0f), s1 = (int)(p1 * 8.0f), s2 = (int)(p2 * 8.0f);
        uint32_t h = ((uint32_t)s0 * 73856093u) ^
                     ((uint32_t)s1 * 19349663u) ^
                     ((uint32_t)s2 * 83492791u);
        uint32_t idx = h & 32767u;
        const float4* e4 = (const float4*)(emb + idx * 16);
        float4 f0 = e4[0], f1 = e4[1], f2 = e4[2], f3 = e4[3];
        float n0 = np[0], n1 = np[1], n2 = np[2];

        int4 A = make_int4(pk(f0.x, f0.y), pk(f0.z, f0.w), pk(f1.x, f1.y), pk(f1.z, f1.w));
        int4 B = make_int4(pk(f2.x, f2.y), pk(f2.z, f2.w), pk(f3.x, f3.y), pk(f3.z, f3.w));
        int4 C = make_int4(pk(n0, n1), pk(n2, 1.0f), 0, 0);  // k=19 -> 1.0 (bias row)
        int4 D = make_int4(0, 0, 0, 0);
        int4* xr = (int4*)(xw + lane * XS);
        xr[0] = A; xr[1] = B; xr[2] = C; xr[3] = D;

        lds_fence();

        #pragma unroll
        for (int sub = 0; sub < 4; ++sub) {
            // ---- L1: h1^T = W1^T @ x^T  (A = W1T regs, B = x row)
            bf16x8 xf = *(const bf16x8*)(xw + (sub * 16 + nn) * XS + q * 8);
            f32x4 acc1[4];
            #pragma unroll
            for (int t = 0; t < 4; ++t) {
                f32x4 z = {0.0f, 0.0f, 0.0f, 0.0f};
                acc1[t] = MFMA16(w1f[t], xf, z);
            }
            // relu -> bf16 -> hw[pt=nn][feat t*16+q*4 .. +3]
            #pragma unroll
            for (int t = 0; t < 4; ++t) {
                float a0 = fmaxf(acc1[t][0], 0.0f), a1 = fmaxf(acc1[t][1], 0.0f);
                float a2 = fmaxf(acc1[t][2], 0.0f), a3 = fmaxf(acc1[t][3], 0.0f);
                int2 w = make_int2(pk(a0, a1), pk(a2, a3));
                *(int2*)(hw + nn * WS + t * 16 + q * 4) = w;
            }
            lds_fence();

            // ---- L2: h2^T = W2^T @ h1^T  (A = W2T regs, B = h1 row)
            bf16x8 h1f0 = *(const bf16x8*)(hw + nn * WS + q * 8);
            bf16x8 h1f1 = *(const bf16x8*)(hw + nn * WS + 32 + q * 8);
            f32x4 acc2[4];
            #pragma unroll
            for (int t = 0; t < 4; ++t) {
                f32x4 c2 = {b2r[t * 4 + 0], b2r[t * 4 + 1], b2r[t * 4 + 2], b2r[t * 4 + 3]};
                c2 = MFMA16(w2f[t][0], h1f0, c2);
                acc2[t] = MFMA16(w2f[t][1], h1f1, c2);
            }
            // relu -> bf16 -> hw[pt=nn][feat] (overwrites h1 AFTER its reads;
            // DS pipe is in-order per wave, and the write data depends on the reads)
            #pragma unroll
            for (int t = 0; t < 4; ++t) {
                float a0 = fmaxf(acc2[t][0], 0.0f), a1 = fmaxf(acc2[t][1], 0.0f);
                float a2 = fmaxf(acc2[t][2], 0.0f), a3 = fmaxf(acc2[t][3], 0.0f);
                int2 w = make_int2(pk(a0, a1), pk(a2, a3));
                *(int2*)(hw + nn * WS + t * 16 + q * 4) = w;
            }
            lds_fence();

            // ---- L3: h3 = h2 @ W3  (A = h2 row, B = W3T regs)
            bf16x8 h2f0 = *(const bf16x8*)(hw + nn * WS + q * 8);
            bf16x8 h2f1 = *(const bf16x8*)(hw + nn * WS + 32 + q * 8);
            f32x4 acc3 = {b3r, b3r, b3r, b3r};
            acc3 = MFMA16(h2f0, w3f[0], acc3);
            acc3 = MFMA16(h2f1, w3f[1], acc3);
            lds_fence();  // protect next sub-tile's h1 writes (WAR across lanes)

            // ---- sigmoid + store: lane (q,nn<3) reg r -> out[pt][nn]
            float o0 = 1.0f / (1.0f + __expf(-acc3[0]));
            float o1 = 1.0f / (1.0f + __expf(-acc3[1]));
            float o2 = 1.0f / (1.0f + __expf(-acc3[2]));
            float o3 = 1.0f / (1.0f + __expf(-acc3[3]));
            if (nn < 3) {
                int p = base + sub * 16 + q * 4;
                out[(p + 0) * 3 + nn] = o0;
                out[(p + 1) * 3 + nn] = o1;
                out[(p + 2) * 3 + nn] = o2;
                out[(p + 3) * 3 + nn] = o3;
            }
        }
        lds_fence();  // xbuf WAR before next tile's staging writes
    }
}

extern "C" void kernel_launch(void* const* d_in, const int* in_sizes, int n_in,
                              void* d_out, int out_size, void* d_ws, size_t ws_size,
                              hipStream_t stream) {
    const float* pos = (const float*)d_in[0];
    const float* nrm = (const float*)d_in[1];
    const float* emb = (const float*)d_in[2];
    const float* W1  = (const float*)d_in[3];
    const float* b1  = (const float*)d_in[4];
    const float* W2  = (const float*)d_in[5];
    const float* b2  = (const float*)d_in[6];
    const float* W3  = (const float*)d_in[7];
    const float* b3  = (const float*)d_in[8];
    float* out = (float*)d_out;

    int n = in_sizes[0] / 3;      // 2,097,152
    int ntiles = n / 64;          // 32768 (N divisible by 64)
    int grid = 768;               // persistent-ish: ~10-11 tiles/wave, 3 blocks/CU
    nrad_mfma_kernel<<<grid, 256, 0, stream>>>(pos, nrm, emb, W1, b1, W2, b2,
                                               W3, b3, out, ntiles);
}